// Round 3
// baseline (8144.074 us; speedup 1.0000x reference)
//
#include <hip/hip_runtime.h>
#include <stdint.h>

// Bidirectional GRU, 6 layers, H=256, S=512, B=10, fp32 in/out (bf16 MFMA inside).
// Only 7 scans matter: fwd 0..5 + bwd 5 (reference slices layer_input[...,:128]).
// Scan s = 4 WGs x 256 thr (64 hidden units each), W frags VGPR-resident.
// ALL inter-WG/inter-scan communication is fence-free: relaxed agent-scope
// atomic u64 words carrying {tag:u32 | h_odd:bf16 | h_even:bf16}. Readers
// retry stale words until tag matches. No fences, no barriers, no flags.

typedef short short8 __attribute__((ext_vector_type(8)));
typedef float floatx4 __attribute__((ext_vector_type(4)));

#define HIDDEN 256
#define SEQ 512
#define BATCH 10

// ws layout (u64 words):
//   hx[scan:7][slot:2][b:16][w:128]   h-exchange ring   (229 KB)
//   xh[scan:5][t:512][b:16][w:64]     layer-out history (20 MB)
#define HX_SCAN (2 * 16 * 128)
#define HX_TOTAL (7 * HX_SCAN)
#define XH_SCAN (SEQ * 16 * 64)

__device__ __forceinline__ unsigned short f2bf(float f) {
    union { float f; unsigned int i; } v; v.f = f;
    unsigned int u = v.i;
    u += 0x7fffu + ((u >> 16) & 1u);   // round-to-nearest-even
    return (unsigned short)(u >> 16);
}
__device__ __forceinline__ short8 ld8f(const float* p) {  // 8 fp32 -> bf16x8 frag
    float4 a = *(const float4*)p;
    float4 b = *(const float4*)(p + 4);
    short8 r;
    r[0] = (short)f2bf(a.x); r[1] = (short)f2bf(a.y);
    r[2] = (short)f2bf(a.z); r[3] = (short)f2bf(a.w);
    r[4] = (short)f2bf(b.x); r[5] = (short)f2bf(b.y);
    r[6] = (short)f2bf(b.z); r[7] = (short)f2bf(b.w);
    return r;
}
__device__ __forceinline__ short8 pack4(unsigned long long w0, unsigned long long w1,
                                        unsigned long long w2, unsigned long long w3) {
    union { unsigned int u[4]; short8 s; } u_;
    u_.u[0] = (unsigned)w0; u_.u[1] = (unsigned)w1;
    u_.u[2] = (unsigned)w2; u_.u[3] = (unsigned)w3;
    return u_.s;
}
__device__ __forceinline__ float sigmoidf_(float x) { return 1.0f / (1.0f + __expf(-x)); }
__device__ __forceinline__ float tanhf_(float x) {
    float e = __expf(2.0f * x);
    return 1.0f - 2.0f / (e + 1.0f);
}

#define ALD(p) __hip_atomic_load((p), __ATOMIC_RELAXED, __HIP_MEMORY_SCOPE_AGENT)
#define AST(p, v) __hip_atomic_store((p), (v), __ATOMIC_RELAXED, __HIP_MEMORY_SCOPE_AGENT)

__global__ __launch_bounds__(256, 1)
void gru_pipeline(const float* __restrict__ x,
                  const float* __restrict__ wihl0,
                  const float* __restrict__ wihrest,
                  const float* __restrict__ whh,
                  float* __restrict__ out,
                  unsigned long long* __restrict__ hx,
                  unsigned long long* __restrict__ xh)
{
    const int scan  = blockIdx.x & 7;   // XCD-affinity heuristic only (speed, not correctness)
    const int chunk = blockIdx.x >> 3;  // 0..3, hidden units [64*chunk, 64*chunk+64)
    if (scan >= 7) return;

    const bool isBwd = (scan == 6);
    const int layer = isBwd ? 5 : scan;
    const int dir = isBwd ? 1 : 0;

    const float* wih; int wih_stride;
    if (layer == 0) { wih = wihl0 + (size_t)dir * 768 * 128; wih_stride = 128; }
    else { wih = wihrest + ((size_t)((layer - 1) * 2 + dir)) * 768 * 512; wih_stride = 512; }
    const float* whhp = whh + ((size_t)(layer * 2 + dir)) * 768 * HIDDEN;

    const int prod = (layer == 0) ? -1 : (layer - 1);
    const unsigned long long* pxh = (prod >= 0) ? (xh + (size_t)prod * XH_SCAN) : nullptr;
    unsigned long long* myxh = (scan < 5) ? (xh + (size_t)scan * XH_SCAN) : nullptr;
    unsigned long long* myhx = hx + (size_t)scan * HX_SCAN;

    const int tid  = threadIdx.x;
    const int wave = tid >> 6;
    const int lane = tid & 63;
    const int n16  = lane & 15;   // gate column within tile / batch row for A frags
    const int quad = lane >> 4;
    const int j = chunk * 64 + wave * 16 + n16;   // this lane's hidden unit

    // ---- W fragments (MFMA B operand), bf16, VGPR-resident ----
    // B[k][n]: n = lane&15 -> gate row (g*256 + j); k = q*32 + quad*8 + i
    short8 bx[3][4];
    short8 bh[3][8];
#pragma unroll
    for (int g = 0; g < 3; ++g) {
        const int row = g * HIDDEN + j;
        const float* wr = wih + (size_t)row * wih_stride;
#pragma unroll
        for (int q = 0; q < 4; ++q) bx[g][q] = ld8f(wr + q * 32 + quad * 8);
        const float* hr = whhp + (size_t)row * HIDDEN;
#pragma unroll
        for (int q = 0; q < 8; ++q) bh[g][q] = ld8f(hr + q * 32 + quad * 8);
    }

    float hprev[4] = {0.f, 0.f, 0.f, 0.f};
    const int bmA = (n16 > 9) ? 9 : n16;  // clamp batch row for layer-0 x loads

    for (int t = 0; t < SEQ; ++t) {
        const int tx = isBwd ? (SEQ - 1 - t) : t;

        // --- issue h(t-1) word loads early (verified later, overlaps x path) ---
        unsigned long long hw[32];
        const unsigned long long* hb_ = myhx + (size_t)((t - 1) & 1) * 2048
                                      + (size_t)n16 * 128 + quad * 4;
        if (t > 0) {
#pragma unroll
            for (int q = 0; q < 8; ++q)
#pragma unroll
                for (int i = 0; i < 4; ++i)
                    hw[q * 4 + i] = ALD(hb_ + q * 16 + i);
        }

        // --- A_x fragments: A[m=batch=lane&15][k=q*32+quad*8+i] ---
        short8 ax[4];
        if (layer == 0) {
            const float* xrow = x + (size_t)tx * (BATCH * 128) + (size_t)bmA * 128;
#pragma unroll
            for (int q = 0; q < 4; ++q) ax[q] = ld8f(xrow + q * 32 + quad * 8);
        } else {
            unsigned long long xw[16];
            const unsigned long long* xb_ = pxh + (size_t)tx * 1024 + (size_t)n16 * 64 + quad * 4;
#pragma unroll
            for (int q = 0; q < 4; ++q)
#pragma unroll
                for (int i = 0; i < 4; ++i)
                    xw[q * 4 + i] = ALD(xb_ + q * 16 + i);
            const unsigned xtag = (unsigned)(tx + 1);
            int spins = 0;
            while (true) {
                bool bad = false;
#pragma unroll
                for (int k2 = 0; k2 < 16; ++k2)
                    if ((unsigned)(xw[k2] >> 32) != xtag) {
                        bad = true;
                        xw[k2] = ALD(xb_ + (k2 >> 2) * 16 + (k2 & 3));
                    }
                if (!bad) break;
                if (++spins > 4) __builtin_amdgcn_s_sleep(2);
            }
#pragma unroll
            for (int q = 0; q < 4; ++q)
                ax[q] = pack4(xw[q * 4], xw[q * 4 + 1], xw[q * 4 + 2], xw[q * 4 + 3]);
        }

        floatx4 cx[3], ch[3];
#pragma unroll
        for (int g = 0; g < 3; ++g) {
            cx[g] = (floatx4){0.f, 0.f, 0.f, 0.f};
            ch[g] = (floatx4){0.f, 0.f, 0.f, 0.f};
        }
#pragma unroll
        for (int g = 0; g < 3; ++g)
#pragma unroll
            for (int q = 0; q < 4; ++q)
                cx[g] = __builtin_amdgcn_mfma_f32_16x16x32_bf16(ax[q], bx[g][q], cx[g], 0, 0, 0);

        // --- verify h words, build A_h frags, MFMA over K=256 ---
        if (t > 0) {
            const unsigned htag = (unsigned)t;
            int spins = 0;
            while (true) {
                bool bad = false;
#pragma unroll
                for (int k2 = 0; k2 < 32; ++k2)
                    if ((unsigned)(hw[k2] >> 32) != htag) {
                        bad = true;
                        hw[k2] = ALD(hb_ + (k2 >> 2) * 16 + (k2 & 3));
                    }
                if (!bad) break;
                if (++spins > 4) __builtin_amdgcn_s_sleep(2);
            }
#pragma unroll
            for (int q = 0; q < 8; ++q) {
                short8 ah = pack4(hw[q * 4], hw[q * 4 + 1], hw[q * 4 + 2], hw[q * 4 + 3]);
#pragma unroll
                for (int g = 0; g < 3; ++g)
                    ch[g] = __builtin_amdgcn_mfma_f32_16x16x32_bf16(ah, bh[g][q], ch[g], 0, 0, 0);
            }
        }

        // --- nonlinearity + h update ---
        // C/D layout: col = lane&15 = hidden unit j, row = quad*4 + reg = batch
        unsigned short hbv[4];
#pragma unroll
        for (int r = 0; r < 4; ++r) {
            const int b = quad * 4 + r;
            float rr = sigmoidf_(cx[0][r] + ch[0][r]);
            float zz = sigmoidf_(cx[1][r] + ch[1][r]);
            float nn = tanhf_(cx[2][r] + rr * ch[2][r]);
            float hn = (1.0f - zz) * nn + zz * hprev[r];
            hprev[r] = hn;
            hbv[r] = f2bf(hn);
            if (scan >= 5 && b < BATCH) {
                // fwd5 -> out cols [0,256); bwd5 in scan order -> [256,512)
                const int col = (scan == 5) ? j : (256 + j);
                out[(size_t)t * (BATCH * 512) + (size_t)b * 512 + col] = hn;
            }
        }

        // --- publish: pair lanes (j, j^1) -> one u64 word per (b, hidden-pair) ---
        unsigned int lov[4];
#pragma unroll
        for (int r = 0; r < 4; ++r) {
            int p = __shfl_xor((int)hbv[r], 1, 64);
            lov[r] = ((unsigned)hbv[r] & 0xffffu) | ((unsigned)p << 16);  // valid on even lanes
        }
        if (!(n16 & 1)) {
            const unsigned long long tag64 = ((unsigned long long)(unsigned)(t + 1)) << 32;
            unsigned long long* hst = myhx + (size_t)(t & 1) * 2048 + (size_t)(j >> 1);
#pragma unroll
            for (int r = 0; r < 4; ++r) {
                const int b = quad * 4 + r;
                AST(hst + (size_t)b * 128, tag64 | lov[r]);
            }
            if (myxh && j < 128) {
                unsigned long long* xst = myxh + (size_t)t * 1024 + (size_t)(j >> 1);
#pragma unroll
                for (int r = 0; r < 4; ++r) {
                    const int b = quad * 4 + r;
                    AST(xst + (size_t)b * 64, tag64 | lov[r]);
                }
            }
        }
        // no barrier, no fence: waves free-run, tags carry correctness
    }
}

extern "C" void kernel_launch(void* const* d_in, const int* in_sizes, int n_in,
                              void* d_out, int out_size, void* d_ws, size_t ws_size,
                              hipStream_t stream) {
    (void)in_sizes; (void)n_in; (void)out_size; (void)ws_size;
    const float* x       = (const float*)d_in[0];
    const float* wihl0   = (const float*)d_in[1];
    const float* wihrest = (const float*)d_in[2];
    const float* whh     = (const float*)d_in[3];
    float* out = (float*)d_out;
    unsigned long long* hx = (unsigned long long*)d_ws;
    unsigned long long* xhp = hx + HX_TOTAL;

    // No memset needed: 0xAA poison never matches any tag (1..512).
    // blockIdx = chunk*8 + scan; scans 0..6 (index 7 idle, keeps %8 XCD affinity)
    gru_pipeline<<<dim3(32), dim3(256), 0, stream>>>(x, wihl0, wihrest, whh, out, hx, xhp);
}

// Round 5
// 7599.843 us; speedup vs baseline: 1.0716x; 1.0716x over previous
//
#include <hip/hip_runtime.h>
#include <stdint.h>

// Bidirectional GRU, 6 layers, H=256, S=512, B=10, fp32 in/out, bf16 MFMA.
// 7 live scans (fwd 0..5 + bwd 5; bwd 0..4 are dead code in the reference).
// One WG per scan: recurrence fully intra-CU (W_hh VGPR/AGPR-resident, LDS
// h-transpose, lgkm-only barriers). Helper WGs compute gates_x off the
// critical path, publish tagged slots via MALL-routed relaxed agent atomics.
// r/z gate x-parts transported bf16; n-gate x-part f32 (tanh slope=1).

typedef short short8 __attribute__((ext_vector_type(8)));
typedef float floatx4 __attribute__((ext_vector_type(4)));
typedef unsigned long long u64;
typedef unsigned int u32;
typedef unsigned short u16;

#define SEQ 512

// ---- workspace (all cross-WG data is u64 words, MALL-routed atomics) ----
// gring: 7 streams x 32 slots x 4096 u64 (2048 rz-bf16 + 2048 nx-f32)  7.3 MB
// hh   : scans 0..4 full-depth h history [t:512][b:16][ch:128] bf16    10.5 MB
// tags : u32  gtag[7][32] @0 ; htag[5][512] @256 ; cpp[7] @2816
#define GSLOT_U64 4096
#define GRING_U64 (7 * 32 * GSLOT_U64)
#define HH_U16 (5 * 512 * 2048)
#define TAGS_OFF_B ((size_t)GRING_U64 * 8 + (size_t)HH_U16 * 2)

__device__ __forceinline__ u16 f2bf(float f){ union{float f;u32 i;}v; v.f=f; u32 u=v.i; u += 0x7fffu + ((u>>16)&1u); return (u16)(u>>16); }
__device__ __forceinline__ float bf2f(u16 h){ union{u32 i;float f;}v; v.i=((u32)h)<<16; return v.f; }
__device__ __forceinline__ short8 ld8f(const float* p){
    float4 a=*(const float4*)p, b=*(const float4*)(p+4);
    short8 r; r[0]=(short)f2bf(a.x); r[1]=(short)f2bf(a.y); r[2]=(short)f2bf(a.z); r[3]=(short)f2bf(a.w);
    r[4]=(short)f2bf(b.x); r[5]=(short)f2bf(b.y); r[6]=(short)f2bf(b.z); r[7]=(short)f2bf(b.w); return r;
}
__device__ __forceinline__ short8 pk2(u64 a, u64 b){ union{u64 q[2]; short8 s;}v; v.q[0]=a; v.q[1]=b; return v.s; }
__device__ __forceinline__ float sigmoidf_(float x){ return 1.0f/(1.0f+__expf(-x)); }
__device__ __forceinline__ float tanhf_(float x){ float e=__expf(2.0f*x); return 1.0f-2.0f/(e+1.0f); }

#define ALD(p)    __hip_atomic_load((p), __ATOMIC_RELAXED, __HIP_MEMORY_SCOPE_AGENT)
#define AST(p,v)  __hip_atomic_store((p),(v),__ATOMIC_RELAXED,__HIP_MEMORY_SCOPE_AGENT)
__device__ __forceinline__ void wait_vm0(){ asm volatile("s_waitcnt vmcnt(0)" ::: "memory"); }
__device__ __forceinline__ void lgkm_barrier(){ asm volatile("s_waitcnt lgkmcnt(0)\n\ts_barrier" ::: "memory"); }

__global__ __launch_bounds__(256, 1)
void gru_pipeline(const float* __restrict__ x,
                  const float* __restrict__ wihl0,
                  const float* __restrict__ wihrest,
                  const float* __restrict__ whh,
                  float* __restrict__ out,
                  u64* __restrict__ gring,
                  u16* __restrict__ hhb,
                  u32* __restrict__ tags)
{
    __shared__ u64 smem_[12352];   // 98,816 B
    const int blk  = blockIdx.x;
    const int tid  = threadIdx.x;
    const int w    = tid >> 6;
    const int lane = tid & 63;
    const int n16  = lane & 15;
    const int quad = lane >> 4;
    u32* cparr = tags + 2816;

    if (blk < 7) {
        // ================= SCAN: one WG per scan =================
        const int s = blk;
        const int layer = (s==6)?5:s, dir=(s==6)?1:0;
        const float* whhp = whh + ((size_t)(layer*2+dir))*768*256;

        // W_hh B-frags: tile tt=g*4+u, gate-row = g*256 + 64w+16u+n16
        short8 bh[12][8];
#pragma unroll
        for (int g=0; g<3; ++g)
#pragma unroll
        for (int u=0; u<4; ++u) {
            const int row = g*256 + 64*w + 16*u + n16;
#pragma unroll
            for (int q=0; q<8; ++q)
                bh[g*4+u][q] = ld8f(whhp + (size_t)row*256 + q*32 + quad*8);
        }

        u16*   gbufRZ = (u16*)smem_;               // [2][512][20] bf16
        float* gbufN  = (float*)(gbufRZ + 20480);  // [2][256][20] f32
        u16*   hbuf   = (u16*)(gbufN + 10240);     // [2][16][264] bf16
        for (int i=tid; i<4224; i+=256) hbuf[i] = 0;   // h(-1)=0

        u32* gtp = tags + s*32;
        u32* htp = tags + 256 + s*512;             // only s<=4 published

        // prologue: stage gates(0) into slot 0
        {
            int gd=0;
            while (ALD(gtp + 0) != 1u){ if(++gd>2000000) break; __builtin_amdgcn_s_sleep(2); }
            u64* gq = gring + (size_t)(s*32)*GSLOT_U64;
            u64 lwA[8], lwB[8];
#pragma unroll
            for (int c=0;c<2;++c){ const int col=2*tid+c;
#pragma unroll
                for (int k=0;k<4;++k) lwA[c*4+k] = ALD(gq + col*4 + k); }
#pragma unroll
            for (int k=0;k<8;++k) lwB[k] = ALD(gq + 2048 + tid*8 + k);
#pragma unroll
            for (int c=0;c<2;++c){ const int col=2*tid+c;
#pragma unroll
                for (int k=0;k<4;++k) *(u64*)(gbufRZ + col*20 + k*4) = lwA[c*4+k]; }
#pragma unroll
            for (int k=0;k<8;++k) *(u64*)(gbufN + tid*20 + k*2) = lwB[k];
        }
        lgkm_barrier();

        float hprev[16];
#pragma unroll
        for (int i=0;i<16;++i) hprev[i]=0.f;

        for (int t=0; t<SEQ; ++t) {
            const bool have_next = (t < SEQ-1);
            // ordered tag publish: h(t-2) stores drained (staging wait_vm0 of
            // step t-1) and barrier-covered (end of t-1) before this.
            if (tid==0) {
                AST(cparr + s, (u32)(t+1));
                if (s<=4 && t>=2) AST(htp + (t-2), (u32)(t-1));
            }
            u32 tg = 0;
            if (have_next) tg = ALD(gtp + ((t+1)&31));   // early poll, used at q==2

            const u16*   gRZ = gbufRZ + (t&1)*10240;
            const float* gN  = gbufN  + (t&1)*5120;
            const u16*   hb  = hbuf   + (t&1)*4224;

            // acc init: r,z x-parts from LDS; n-gate h-part accumulates from 0
            floatx4 acc[12];
#pragma unroll
            for (int g=0; g<2; ++g)
#pragma unroll
            for (int u=0; u<4; ++u) {
                const u64 gw = *(const u64*)(gRZ + (g*256 + 64*w + 16*u + n16)*20 + quad*4);
#pragma unroll
                for (int r=0; r<4; ++r) acc[g*4+u][r] = bf2f((u16)(gw >> (16*r)));
            }
#pragma unroll
            for (int tt=8; tt<12; ++tt) acc[tt] = (floatx4){0.f,0.f,0.f,0.f};

            bool hit = false; u64 lwA[8], lwB[8];
#pragma unroll
            for (int q=0; q<8; ++q) {
                short8 ah = *(const short8*)(hb + n16*264 + q*32 + quad*8);
#pragma unroll
                for (int tt=0; tt<12; ++tt)
                    acc[tt] = __builtin_amdgcn_mfma_f32_16x16x32_bf16(ah, bh[tt][q], acc[tt], 0,0,0);
                if (q==2 && have_next) {
                    hit = (tg == (u32)(t+2));
                    if (hit) {
                        u64* gq = gring + (size_t)(s*32 + ((t+1)&31))*GSLOT_U64;
#pragma unroll
                        for (int c=0;c<2;++c){ const int col=2*tid+c;
#pragma unroll
                            for (int k=0;k<4;++k) lwA[c*4+k] = ALD(gq + col*4 + k); }
                    }
                }
                if (q==5 && hit) {
                    u64* gq = gring + (size_t)(s*32 + ((t+1)&31))*GSLOT_U64;
#pragma unroll
                    for (int k=0;k<8;++k) lwB[k] = ALD(gq + 2048 + tid*8 + k);
                }
            }

            // nonlinearity (nx f32 from LDS; hprev kept unrounded f32)
            u16 hbv[16]; float hnv[16];
#pragma unroll
            for (int u=0; u<4; ++u)
#pragma unroll
            for (int r=0; r<4; ++r) {
                const int idx=u*4+r;
                float rr = sigmoidf_(acc[u][r]);
                float zz = sigmoidf_(acc[4+u][r]);
                float nx = gN[(64*w + 16*u + n16)*20 + quad*4 + r];
                float nn = tanhf_(nx + rr*acc[8+u][r]);
                float hn = (1.0f-zz)*nn + zz*hprev[idx];
                hprev[idx]=hn; hbv[idx]=f2bf(hn); hnv[idx]=hn;
            }

            // stage gates(t+1) into the other LDS slot
            if (have_next) {
                if (!hit) {
                    int gd=0;
                    while (ALD(gtp + ((t+1)&31)) != (u32)(t+2)){ if(++gd>4000000) break; __builtin_amdgcn_s_sleep(1); }
                    u64* gq = gring + (size_t)(s*32 + ((t+1)&31))*GSLOT_U64;
#pragma unroll
                    for (int c=0;c<2;++c){ const int col=2*tid+c;
#pragma unroll
                        for (int k=0;k<4;++k) lwA[c*4+k] = ALD(gq + col*4 + k); }
#pragma unroll
                    for (int k=0;k<8;++k) lwB[k] = ALD(gq + 2048 + tid*8 + k);
                }
                wait_vm0();   // drains lw loads + h(t-1) stores (issued ~1 step ago)
                u16*   dRZ = gbufRZ + ((t+1)&1)*10240;
                float* dN  = gbufN  + ((t+1)&1)*5120;
#pragma unroll
                for (int c=0;c<2;++c){ const int col=2*tid+c;
#pragma unroll
                    for (int k=0;k<4;++k) *(u64*)(dRZ + col*20 + k*4) = lwA[c*4+k]; }
#pragma unroll
                for (int k=0;k<8;++k) *(u64*)(dN + tid*20 + k*2) = lwB[k];
            } else {
                wait_vm0();
            }

            // h(t) -> LDS for next step (all 256 channels)
            u16* hn_ = hbuf + ((t+1)&1)*4224;
#pragma unroll
            for (int u=0; u<4; ++u)
#pragma unroll
            for (int r=0; r<4; ++r)
                hn_[(quad*4+r)*264 + 64*w + 16*u + n16] = hbv[u*4+r];

            // publish h ch 0..127 (scans 0..4, waves 0..1 ONLY) or write output
            if (s<=4) {
                if (w < 2) {
                    u32 pw[16];
#pragma unroll
                    for (int i2=0;i2<16;++i2) pw[i2] = (u32)(u16)__shfl_xor((int)hbv[i2], 1, 64);
                    u32* hq = (u32*)(hhb + (size_t)s*1048576 + (size_t)t*2048);
                    if (!(n16 & 1)) {
#pragma unroll
                        for (int u=0; u<4; ++u)
#pragma unroll
                        for (int r=0; r<4; ++r) {
                            const int idx=u*4+r;
                            const int j = 64*w + 16*u + n16;     // < 128
                            AST(hq + (quad*4+r)*64 + (j>>1), (u32)hbv[idx] | (pw[idx]<<16));
                        }
                    }
                }
            } else {
                const int off = (s==6)?256:0;
#pragma unroll
                for (int u=0; u<4; ++u)
#pragma unroll
                for (int r=0; r<4; ++r) {
                    const int b = quad*4+r;
                    if (b < 10)
                        out[(size_t)t*5120 + (size_t)b*512 + off + 64*w + 16*u + n16] = hnv[u*4+r];
                }
            }
            lgkm_barrier();
        }
        // epilogue: drain final h stores, then publish last two h tags
        wait_vm0(); lgkm_barrier();
        if (tid==0 && s<=4) { AST(htp + 510, 511u); AST(htp + 511, 512u); }
        return;
    }

    // ================= HELPERS: gates_x producers =================
    int sh, t0, tstep;
    if (blk < 11) { sh = 0; t0 = blk - 7;        tstep = 4; }
    else          { sh = 1 + (blk-11)/2; t0 = (blk-11)&1; tstep = 2; }

    const int layer = (sh==6)?5:sh, dir=(sh==6)?1:0;
    const float* wihp; int stride;
    if (layer==0){ wihp = wihl0 + (size_t)dir*768*128; stride=128; }
    else         { wihp = wihrest + ((size_t)((layer-1)*2+dir))*768*512; stride=512; }

    short8 bxf[12][4];
#pragma unroll
    for (int tt=0; tt<12; ++tt) {
        const int gcol = 192*w + 16*tt + n16;
#pragma unroll
        for (int q=0; q<4; ++q)
            bxf[tt][q] = ld8f(wihp + (size_t)gcol*stride + q*32 + quad*8);
    }
    u16*   tbufRZ = (u16*)smem_;                 // [512][16] bf16
    float* tbufN  = (float*)(tbufRZ + 512*16);   // [256][16] f32
    const int bmA = (n16>9)?9:n16;
    const int lsrc = (sh==6)? 4 : (sh-1);

    for (int t = t0; t < SEQ; t += tstep) {
        if (t >= 32) {   // ring-32 flow control vs consumer scan (all streams)
            int gd=0;
            while ((int)ALD(cparr + sh) < t-24){ if(++gd>2000000) break; __builtin_amdgcn_s_sleep(8); }
        }
        short8 ax[4];
        if (sh == 0) {
            const float* xr = x + (size_t)t*1280 + (size_t)bmA*128;
#pragma unroll
            for (int q=0; q<4; ++q) ax[q] = ld8f(xr + q*32 + quad*8);
        } else {
            const int srct = (sh==6)? (SEQ-1-t) : t;
            int gd=0;
            while (ALD(tags + 256 + lsrc*512 + srct) != (u32)(srct+1)){ if(++gd>2000000) break; __builtin_amdgcn_s_sleep(4); }
            const u64* hq = (const u64*)(hhb + (size_t)lsrc*1048576 + (size_t)srct*2048);
#pragma unroll
            for (int q=0; q<4; ++q) {
                u64 a = ALD(hq + n16*32 + q*8 + quad*2);
                u64 b = ALD(hq + n16*32 + q*8 + quad*2 + 1);
                ax[q] = pk2(a, b);
            }
        }
        floatx4 acc[12];
#pragma unroll
        for (int tt=0; tt<12; ++tt) acc[tt] = (floatx4){0.f,0.f,0.f,0.f};
#pragma unroll
        for (int q=0; q<4; ++q)
#pragma unroll
            for (int tt=0; tt<12; ++tt)
                acc[tt] = __builtin_amdgcn_mfma_f32_16x16x32_bf16(ax[q], bxf[tt][q], acc[tt], 0,0,0);

        // transpose to [col][b] in LDS (rz as bf16, nx as f32)
#pragma unroll
        for (int tt=0; tt<12; ++tt) {
            const int gcol = 192*w + 16*tt + n16;
            if (gcol < 512) {
#pragma unroll
                for (int r=0; r<4; ++r) tbufRZ[gcol*16 + quad*4 + r] = f2bf(acc[tt][r]);
            } else {
#pragma unroll
                for (int r=0; r<4; ++r) tbufN[(gcol-512)*16 + quad*4 + r] = acc[tt][r];
            }
        }
        __syncthreads();
        u64* gq = gring + (size_t)(sh*32 + (t&31))*GSLOT_U64;
#pragma unroll
        for (int c=0;c<2;++c){ const int col=2*tid+c;
#pragma unroll
            for (int k=0;k<4;++k) AST(gq + col*4 + k, *(const u64*)(tbufRZ + col*16 + k*4)); }
#pragma unroll
        for (int k=0;k<8;++k) AST(gq + 2048 + tid*8 + k, *(const u64*)(tbufN + tid*16 + k*2));
        wait_vm0();
        __syncthreads();
        if (tid==0) AST(tags + sh*32 + (t&31), (u32)(t+1));
        __syncthreads();
    }
}

extern "C" void kernel_launch(void* const* d_in, const int* in_sizes, int n_in,
                              void* d_out, int out_size, void* d_ws, size_t ws_size,
                              hipStream_t stream) {
    (void)in_sizes; (void)n_in; (void)out_size; (void)ws_size;
    const float* x       = (const float*)d_in[0];
    const float* wihl0   = (const float*)d_in[1];
    const float* wihrest = (const float*)d_in[2];
    const float* whh     = (const float*)d_in[3];
    float* out = (float*)d_out;
    u64* gring = (u64*)d_ws;
    u16* hhb   = (u16*)((char*)d_ws + (size_t)GRING_U64*8);
    u32* tags  = (u32*)((char*)d_ws + TAGS_OFF_B);

    // No memset needed: 0xAAAAAAAA poison never equals a valid tag (1..512),
    // and flow-control reads cast to int (poison is negative => "not yet").
    gru_pipeline<<<dim3(23), dim3(256), 0, stream>>>(x, wihl0, wihrest, whh, out,
                                                     gring, hhb, tags);
}

// Round 6
// 4457.591 us; speedup vs baseline: 1.8270x; 1.7049x over previous
//
#include <hip/hip_runtime.h>
#include <stdint.h>

// Bidirectional GRU, 6 layers, H=256, S=512, B=10, fp32 in/out, bf16 MFMA.
// 7 live scans (fwd 0..5 + bwd 5). One 512-thread WG per scan: recurrence
// fully intra-CU. 8 waves x 6 tiles => W_hh frags = 192 VGPR/wave (fits the
// 256-reg cap at 2 waves/SIMD; round-5's 4-wave split needed ~470 => spill).
// Gates staged by helper WGs, consumed via global_load_lds (SC1 aux: MALL-
// coherent, bypasses stale per-XCD L2). Cross-CU data: SC1 atomics + tags.

typedef short short8 __attribute__((ext_vector_type(8)));
typedef float floatx4 __attribute__((ext_vector_type(4)));
typedef unsigned long long u64;
typedef unsigned int u32;
typedef unsigned short u16;

#define SEQ 512

// ws: gring 7*32 slots x 32KB (rz bf16 [512][16] + nx f32 [256][16]) = 7.34MB
//     hh   scans 0..4 [t:512][b:16][ch:128] bf16 = 10.5MB
//     tags u32: gtag[7][32] @0 ; htag[5][512] @256 ; cparr[7] @2816
#define GSLOT_U64 4096
#define GRING_U64 (7 * 32 * GSLOT_U64)
#define HH_U16 (5 * 512 * 2048)
#define TAGS_OFF_B ((size_t)GRING_U64 * 8 + (size_t)HH_U16 * 2)

__device__ __forceinline__ u16 f2bf(float f){ union{float f;u32 i;}v; v.f=f; u32 u=v.i; u += 0x7fffu + ((u>>16)&1u); return (u16)(u>>16); }
__device__ __forceinline__ float bf2f(u16 h){ union{u32 i;float f;}v; v.i=((u32)h)<<16; return v.f; }
__device__ __forceinline__ short8 ld8f(const float* p){
    float4 a=*(const float4*)p, b=*(const float4*)(p+4);
    short8 r; r[0]=(short)f2bf(a.x); r[1]=(short)f2bf(a.y); r[2]=(short)f2bf(a.z); r[3]=(short)f2bf(a.w);
    r[4]=(short)f2bf(b.x); r[5]=(short)f2bf(b.y); r[6]=(short)f2bf(b.z); r[7]=(short)f2bf(b.w); return r;
}
__device__ __forceinline__ short8 pk2(u64 a, u64 b){ union{u64 q[2]; short8 s;}v; v.q[0]=a; v.q[1]=b; return v.s; }
__device__ __forceinline__ u64 pack4bf(floatx4 a){
    return (u64)f2bf(a[0]) | ((u64)f2bf(a[1])<<16) | ((u64)f2bf(a[2])<<32) | ((u64)f2bf(a[3])<<48);
}
__device__ __forceinline__ float sigmoidf_(float x){ return 1.0f/(1.0f+__expf(-x)); }
__device__ __forceinline__ float tanhf_(float x){ float e=__expf(2.0f*x); return 1.0f-2.0f/(e+1.0f); }

#define ALD(p)    __hip_atomic_load((p), __ATOMIC_RELAXED, __HIP_MEMORY_SCOPE_AGENT)
#define AST(p,v)  __hip_atomic_store((p),(v),__ATOMIC_RELAXED,__HIP_MEMORY_SCOPE_AGENT)
__device__ __forceinline__ void wait_vm0(){ asm volatile("s_waitcnt vmcnt(0)" ::: "memory"); }
__device__ __forceinline__ void lgkm_barrier(){ asm volatile("s_waitcnt lgkmcnt(0)\n\ts_barrier" ::: "memory"); }

// global->LDS DMA, 16B/lane, aux=16 (SC1: device-scope, bypass per-XCD L2)
__device__ __forceinline__ void dma16(const void* g, void* l) {
    __builtin_amdgcn_global_load_lds(
        reinterpret_cast<const __attribute__((address_space(1))) unsigned int*>(
            (uintptr_t)g),
        reinterpret_cast<__attribute__((address_space(3))) unsigned int*>(
            (uintptr_t)l), 16, 0, 16);
}

__global__ __launch_bounds__(512, 2)
void gru_pipeline(const float* __restrict__ x,
                  const float* __restrict__ wihl0,
                  const float* __restrict__ wihrest,
                  const float* __restrict__ whh,
                  float* __restrict__ out,
                  u64* __restrict__ gring,
                  u16* __restrict__ hhb,
                  u32* __restrict__ tags)
{
    __shared__ u64 smem_[10304];   // 82,432 B: gbuf 2x32768 + hbuf 16,896
    const int blk  = blockIdx.x;
    const int tid  = threadIdx.x;
    const int w    = tid >> 6;
    const int lane = tid & 63;
    const int n16  = lane & 15;
    const int quad = lane >> 4;
    u32* cparr = tags + 2816;

    if (blk < 7) {
        // ================= SCAN: one 512-thread WG per scan =================
        const int s = blk;
        const int layer = (s==6)?5:s, dir=(s==6)?1:0;
        const float* whhp = whh + ((size_t)(layer*2+dir))*768*256;

        // W_hh B-frags: wave owns units j in [32w,32w+32): tiles m=g*2+u,
        // gate-row = g*256 + 32w + 16u + n16
        short8 bh[6][8];
#pragma unroll
        for (int g=0; g<3; ++g)
#pragma unroll
        for (int u=0; u<2; ++u) {
            const int row = g*256 + 32*w + 16*u + n16;
#pragma unroll
            for (int q=0; q<8; ++q)
                bh[g*2+u][q] = ld8f(whhp + (size_t)row*256 + q*32 + quad*8);
        }

        char* gb   = (char*)smem_;            // gate slots: [2][32768 B]
        u16*  hbuf = (u16*)(gb + 65536);      // [2][16][264] bf16
        for (int i=tid; i<8448; i+=512) hbuf[i] = 0;   // h(-1)=0 (both slots)

        u32* gtp = tags + s*32;
        u32* htp = tags + 256 + s*512;

        // prologue: stage gates(0)
        {
            int gd=0;
            while (ALD(gtp + 0) != 1u){ if(++gd>3000000) break; __builtin_amdgcn_s_sleep(2); }
            const char* sg = (const char*)(gring + (size_t)(s*32)*GSLOT_U64);
#pragma unroll
            for (int r=0; r<4; ++r) dma16(sg + (r*512+tid)*16, gb + (r*512+tid)*16);
            wait_vm0(); lgkm_barrier();
        }

        for (int t=0; t<SEQ; ++t) {
            // A: tags (h(t-2) stores were issued at t-1 top, drained by t-1 end)
            if (tid==0) {
                AST(cparr + s, (u32)(t+1));
                if (s<=4 && t>=2) AST(htp + (t-2), (u32)(t-1));
            }
            // B: publish h(t-1) to hh / out(t-1), read from LDS slot t&1
            const u16* hbP = hbuf + (t&1)*4224;
            if (t >= 1) {
                if (s<=4) {
                    if (w < 4) {   // tid<256; i2=tid: b=tid&15, 4 j-pairs each
                        const int b = tid & 15, p4 = tid >> 4;
                        u32* hq = (u32*)(hhb + (size_t)s*1048576 + (size_t)(t-1)*2048);
#pragma unroll
                        for (int k=0;k<4;++k) {
                            const int p = p4*4 + k;
                            AST(hq + b*64 + p, *(const u32*)(hbP + b*264 + 2*p));
                        }
                    }
                } else {
                    const int off = (s==6)?256:0;
#pragma unroll
                    for (int k=0;k<5;++k) {
                        const int idx = tid + 512*k, b = idx >> 8, j = idx & 255;
                        if (b < 10)
                            out[(size_t)(t-1)*5120 + (size_t)b*512 + off + j] = bf2f(hbP[b*264 + j]);
                    }
                }
            }
            // C: DMA gates(t+1) into the other gbuf slot (latency hides under MFMA)
            if (t < SEQ-1) {
                int gd=0;
                while (ALD(gtp + ((t+1)&31)) != (u32)(t+2)){ if(++gd>3000000) break; __builtin_amdgcn_s_sleep(1); }
                const char* sg = (const char*)(gring + (size_t)(s*32 + ((t+1)&31))*GSLOT_U64);
                char* dg = gb + ((t+1)&1)*32768;
#pragma unroll
                for (int r=0; r<4; ++r) dma16(sg + (r*512+tid)*16, dg + (r*512+tid)*16);
            }
            // D: acc init (r,z x-parts) + 48 MFMAs over K=256
            const char* g0 = gb + (t&1)*32768;
            floatx4 acc[6];
#pragma unroll
            for (int g=0; g<2; ++g)
#pragma unroll
            for (int u=0; u<2; ++u) {
                const int col = g*256 + 32*w + 16*u + n16;
                const u64 gw = *(const u64*)(g0 + col*32 + quad*8);
#pragma unroll
                for (int r=0; r<4; ++r) acc[g*2+u][r] = bf2f((u16)(gw >> (16*r)));
            }
            acc[4] = (floatx4){0.f,0.f,0.f,0.f};
            acc[5] = (floatx4){0.f,0.f,0.f,0.f};
#pragma unroll
            for (int q=0; q<8; ++q) {
                short8 ah = *(const short8*)(hbP + n16*264 + q*32 + quad*8);
#pragma unroll
                for (int m=0; m<6; ++m)
                    acc[m] = __builtin_amdgcn_mfma_f32_16x16x32_bf16(ah, bh[m][q], acc[m], 0,0,0);
            }
            // E/F: nonlinearity, h(t) -> LDS slot (t+1)&1
            u16* hbN = hbuf + ((t+1)&1)*4224;
            const float* nxp = (const float*)(g0 + 16384);
#pragma unroll
            for (int u=0; u<2; ++u) {
                const int j = 32*w + 16*u + n16;
                const floatx4 nx4 = *(const floatx4*)(nxp + j*16 + quad*4);
#pragma unroll
                for (int r=0; r<4; ++r) {
                    const int b = quad*4 + r;
                    float rr = sigmoidf_(acc[u][r]);
                    float zz = sigmoidf_(acc[2+u][r]);
                    float nn = tanhf_(nx4[r] + rr*acc[4+u][r]);
                    float hp = bf2f(hbP[b*264 + j]);
                    float hn = (1.0f-zz)*nn + zz*hp;
                    hbN[b*264 + j] = f2bf(hn);
                }
            }
            // G: drain DMA (+old stores), then LDS barrier
            wait_vm0();
            lgkm_barrier();
        }
        // epilogue: h(511)/out(511) live in slot 0
        const u16* hbL = hbuf;
        if (s<=4) {
            if (w < 4) {
                const int b = tid & 15, p4 = tid >> 4;
                u32* hq = (u32*)(hhb + (size_t)s*1048576 + (size_t)(SEQ-1)*2048);
#pragma unroll
                for (int k=0;k<4;++k) {
                    const int p = p4*4 + k;
                    AST(hq + b*64 + p, *(const u32*)(hbL + b*264 + 2*p));
                }
            }
        } else {
            const int off = (s==6)?256:0;
#pragma unroll
            for (int k=0;k<5;++k) {
                const int idx = tid + 512*k, b = idx >> 8, j = idx & 255;
                if (b < 10)
                    out[(size_t)(SEQ-1)*5120 + (size_t)b*512 + off + j] = bf2f(hbL[b*264 + j]);
            }
        }
        wait_vm0(); lgkm_barrier();
        if (tid==0 && s<=4) { AST(htp + 510, 511u); AST(htp + 511, 512u); }
        return;
    }

    // ================= HELPERS: gates_x producers =================
    int sh, t0, tstep;
    if (blk < 11) { sh = 0; t0 = blk - 7;        tstep = 4; }
    else          { sh = 1 + (blk-11)/2; t0 = (blk-11)&1; tstep = 2; }

    const int layer = (sh==6)?5:sh, dir=(sh==6)?1:0;
    const float* wihp; int stride;
    if (layer==0){ wihp = wihl0 + (size_t)dir*768*128; stride=128; }
    else         { wihp = wihrest + ((size_t)((layer-1)*2+dir))*768*512; stride=512; }

    // 8 waves x 6 tiles: gate col = (w*6+i)*16 + n16
    short8 bxf[6][4];
#pragma unroll
    for (int i=0; i<6; ++i) {
        const int col = (w*6+i)*16 + n16;
#pragma unroll
        for (int q=0; q<4; ++q)
            bxf[i][q] = ld8f(wihp + (size_t)col*stride + q*32 + quad*8);
    }
    char* tb = (char*)smem_;               // 32 KB slot image
    const int bmA = (n16>9)?9:n16;
    const int lsrc = (sh==6)? 4 : (sh-1);

    for (int t = t0; t < SEQ; t += tstep) {
        if (t >= 32) {   // ring-32 flow control vs consumer scan
            int gd=0;
            while ((int)ALD(cparr + sh) < t-24){ if(++gd>1000000) break; __builtin_amdgcn_s_sleep(8); }
        }
        short8 ax[4];
        if (sh == 0) {
            const float* xr = x + (size_t)t*1280 + (size_t)bmA*128;
#pragma unroll
            for (int q=0; q<4; ++q) ax[q] = ld8f(xr + q*32 + quad*8);
        } else {
            const int srct = (sh==6)? (SEQ-1-t) : t;
            int gd=0;
            while (ALD(tags + 256 + lsrc*512 + srct) != (u32)(srct+1)){ if(++gd>3000000) break; __builtin_amdgcn_s_sleep(4); }
            const u64* hq = (const u64*)(hhb + (size_t)lsrc*1048576 + (size_t)srct*2048);
#pragma unroll
            for (int q=0; q<4; ++q) {
                u64 a = ALD(hq + n16*32 + q*8 + quad*2);
                u64 b = ALD(hq + n16*32 + q*8 + quad*2 + 1);
                ax[q] = pk2(a, b);
            }
        }
        floatx4 acc[6];
#pragma unroll
        for (int i=0; i<6; ++i) acc[i] = (floatx4){0.f,0.f,0.f,0.f};
#pragma unroll
        for (int q=0; q<4; ++q)
#pragma unroll
            for (int i=0; i<6; ++i)
                acc[i] = __builtin_amdgcn_mfma_f32_16x16x32_bf16(ax[q], bxf[i][q], acc[i], 0,0,0);

        // write slot image in LDS: rz bf16 [col<512][16], nx f32 [col-512][16]
#pragma unroll
        for (int i=0; i<6; ++i) {
            const int col = (w*6+i)*16 + n16;
            if (col < 512) *(u64*)(tb + col*32 + quad*8) = pack4bf(acc[i]);
            else           *(floatx4*)(tb + 16384 + (col-512)*64 + quad*16) = acc[i];
        }
        __syncthreads();
        u64* gq = gring + (size_t)(sh*32 + (t&31))*GSLOT_U64;
#pragma unroll
        for (int k=0;k<8;++k) AST(gq + tid*8 + k, ((const u64*)tb)[tid*8 + k]);
        wait_vm0();
        __syncthreads();
        if (tid==0) AST(tags + sh*32 + (t&31), (u32)(t+1));
        __syncthreads();
    }
}

extern "C" void kernel_launch(void* const* d_in, const int* in_sizes, int n_in,
                              void* d_out, int out_size, void* d_ws, size_t ws_size,
                              hipStream_t stream) {
    (void)in_sizes; (void)n_in; (void)out_size; (void)ws_size;
    const float* x       = (const float*)d_in[0];
    const float* wihl0   = (const float*)d_in[1];
    const float* wihrest = (const float*)d_in[2];
    const float* whh     = (const float*)d_in[3];
    float* out = (float*)d_out;
    u64* gring = (u64*)d_ws;
    u16* hhb   = (u16*)((char*)d_ws + (size_t)GRING_U64*8);
    u32* tags  = (u32*)((char*)d_ws + TAGS_OFF_B);

    // No memset: 0xAAAAAAAA poison never equals a valid tag (1..512);
    // flow-control reads cast to int (poison negative => "not yet").
    gru_pipeline<<<dim3(23), dim3(512), 0, stream>>>(x, wihl0, wihrest, whh, out,
                                                     gring, hhb, tags);
}

// Round 7
// 3968.975 us; speedup vs baseline: 2.0519x; 1.1231x over previous
//
#include <hip/hip_runtime.h>
#include <stdint.h>

// Bidirectional GRU, 6 layers, H=256, S=512, B=10, fp32 in/out, bf16 MFMA.
// 7 live scans (fwd 0..5 + bwd 5). One 512-thread WG per scan: recurrence
// intra-CU (W_hh frags in unified VGPR/AGPR file: 192 + ~60 working = 256).
// Gates staged by helper WGs (3 per stream), consumed via global_load_lds
// (SC1: MALL-coherent). KEY (this round): depth-2 gate prefetch with 3 LDS
// slots + partial s_waitcnt vmcnt(4) => zero serialized MALL RTTs per step.
// Ordering: vmcnt(4) drains all ops older than the 4 fresh DMAs (stores
// included) before the barrier; tags published next step => data-before-tag.

typedef short short8 __attribute__((ext_vector_type(8)));
typedef float floatx4 __attribute__((ext_vector_type(4)));
typedef unsigned long long u64;
typedef unsigned int u32;
typedef unsigned short u16;

#define SEQ 512

// ws: gring 7*32 slots x 32KB (rz bf16 [512][16] + nx f32 [256][16]) = 7.34MB
//     hh   scans 0..4 [t:512][b:16][ch:128] bf16 = 10.5MB
//     tags u32: gtag[7][32] @0 ; htag[5][512] @256 ; cparr[7] @2816
#define GSLOT_U64 4096
#define GRING_U64 (7 * 32 * GSLOT_U64)
#define HH_U16 (5 * 512 * 2048)
#define TAGS_OFF_B ((size_t)GRING_U64 * 8 + (size_t)HH_U16 * 2)

__device__ __forceinline__ u16 f2bf(float f){ union{float f;u32 i;}v; v.f=f; u32 u=v.i; u += 0x7fffu + ((u>>16)&1u); return (u16)(u>>16); }
__device__ __forceinline__ float bf2f(u16 h){ union{u32 i;float f;}v; v.i=((u32)h)<<16; return v.f; }
__device__ __forceinline__ short8 ld8f(const float* p){
    float4 a=*(const float4*)p, b=*(const float4*)(p+4);
    short8 r; r[0]=(short)f2bf(a.x); r[1]=(short)f2bf(a.y); r[2]=(short)f2bf(a.z); r[3]=(short)f2bf(a.w);
    r[4]=(short)f2bf(b.x); r[5]=(short)f2bf(b.y); r[6]=(short)f2bf(b.z); r[7]=(short)f2bf(b.w); return r;
}
__device__ __forceinline__ short8 pk2(u64 a, u64 b){ union{u64 q[2]; short8 s;}v; v.q[0]=a; v.q[1]=b; return v.s; }
__device__ __forceinline__ u64 pack4bf(floatx4 a){
    return (u64)f2bf(a[0]) | ((u64)f2bf(a[1])<<16) | ((u64)f2bf(a[2])<<32) | ((u64)f2bf(a[3])<<48);
}
__device__ __forceinline__ float sigmoidf_(float x){ return 1.0f/(1.0f+__expf(-x)); }
__device__ __forceinline__ float tanhf_(float x){ float e=__expf(2.0f*x); return 1.0f-2.0f/(e+1.0f); }

#define ALD(p)    __hip_atomic_load((p), __ATOMIC_RELAXED, __HIP_MEMORY_SCOPE_AGENT)
#define AST(p,v)  __hip_atomic_store((p),(v),__ATOMIC_RELAXED,__HIP_MEMORY_SCOPE_AGENT)
__device__ __forceinline__ void wait_vm0(){ asm volatile("s_waitcnt vmcnt(0)" ::: "memory"); }
__device__ __forceinline__ void wait_vm4(){ asm volatile("s_waitcnt vmcnt(4)" ::: "memory"); }
__device__ __forceinline__ void lgkm_barrier(){ asm volatile("s_waitcnt lgkmcnt(0)\n\ts_barrier" ::: "memory"); }

// global->LDS DMA, 16B/lane, aux=16 (SC1: device-scope, bypass per-XCD L2)
__device__ __forceinline__ void dma16(const void* g, void* l) {
    __builtin_amdgcn_global_load_lds(
        reinterpret_cast<const __attribute__((address_space(1))) unsigned int*>(
            (uintptr_t)g),
        reinterpret_cast<__attribute__((address_space(3))) unsigned int*>(
            (uintptr_t)l), 16, 0, 16);
}

__global__ __launch_bounds__(512, 2)
void gru_pipeline(const float* __restrict__ x,
                  const float* __restrict__ wihl0,
                  const float* __restrict__ wihrest,
                  const float* __restrict__ whh,
                  float* __restrict__ out,
                  u64* __restrict__ gring,
                  u16* __restrict__ hhb,
                  u32* __restrict__ tags)
{
    __shared__ u64 smem_[14400];   // 115,200 B: gbuf 3x32768 + hbuf 16,896 (=> 1 block/CU)
    const int blk  = blockIdx.x;
    const int tid  = threadIdx.x;
    const int w    = tid >> 6;
    const int lane = tid & 63;
    const int n16  = lane & 15;
    const int quad = lane >> 4;
    u32* cparr = tags + 2816;

    if (blk < 7) {
        // ================= SCAN: one 512-thread WG per scan =================
        const int s = blk;
        const int layer = (s==6)?5:s, dir=(s==6)?1:0;
        const float* whhp = whh + ((size_t)(layer*2+dir))*768*256;

        // W_hh B-frags: wave owns units j in [32w,32w+32): tiles m=g*2+u
        short8 bh[6][8];
#pragma unroll
        for (int g=0; g<3; ++g)
#pragma unroll
        for (int u=0; u<2; ++u) {
            const int row = g*256 + 32*w + 16*u + n16;
#pragma unroll
            for (int q=0; q<8; ++q)
                bh[g*2+u][q] = ld8f(whhp + (size_t)row*256 + q*32 + quad*8);
        }

        char* gb   = (char*)smem_;            // gate slots: [3][32768 B]
        u16*  hbuf = (u16*)(gb + 98304);      // [2][16][264] bf16
        for (int i=tid; i<8448; i+=512) hbuf[i] = 0;   // h(-1)=0 (both slots)

        u32* gtp = tags + s*32;
        u32* htp = tags + 256 + s*512;

        // prologue: stage gates(0) and gates(1)
        {
            int gd=0;
            while (ALD(gtp + 0) != 1u){ if(++gd>3000000) break; __builtin_amdgcn_s_sleep(2); }
            const char* sg = (const char*)(gring + (size_t)(s*32)*GSLOT_U64);
#pragma unroll
            for (int r=0; r<4; ++r) dma16(sg + (r*512+tid)*16, gb + (r*512+tid)*16);
            gd=0;
            while (ALD(gtp + 1) != 2u){ if(++gd>3000000) break; __builtin_amdgcn_s_sleep(2); }
            sg = (const char*)(gring + (size_t)(s*32 + 1)*GSLOT_U64);
#pragma unroll
            for (int r=0; r<4; ++r) dma16(sg + (r*512+tid)*16, gb + 32768 + (r*512+tid)*16);
            wait_vm0(); lgkm_barrier();
        }

        for (int t=0; t<SEQ; ++t) {
            // A: tags. h(t-2) data drained by end of step t-1 (vmcnt partial).
            if (tid==0) {
                AST(cparr + s, (u32)(t+1));
                if (s<=4 && t>=2) AST(htp + (t-2), (u32)(t-1));
            }
            // early poll of gtag(t+2); value consumed at phase F
            const bool need2 = (t+2 < SEQ);
            u32 tg2 = 0;
            if (need2) tg2 = ALD(gtp + ((t+2)&31));

            // B: publish h(t-1) / out(t-1) from LDS slot t&1
            const u16* hbP = hbuf + (t&1)*4224;
            if (t >= 1) {
                if (s<=4) {
                    if (tid < 256) {        // b = tid&15, word-pair k = tid>>4
                        const int b = tid & 15, k = tid >> 4;
                        u64* hq = (u64*)(hhb + (size_t)s*1048576 + (size_t)(t-1)*2048);
                        AST(hq + b*32 + 2*k,     *(const u64*)(hbP + b*264 + 8*k));
                        AST(hq + b*32 + 2*k + 1, *(const u64*)(hbP + b*264 + 8*k + 4));
                    }
                } else {
                    const int off = (s==6)?256:0;
#pragma unroll
                    for (int k=0;k<5;++k) {
                        const int idx = tid + 512*k, b = idx >> 8, j = idx & 255;
                        if (b < 10)
                            out[(size_t)(t-1)*5120 + (size_t)b*512 + off + j] = bf2f(hbP[b*264 + j]);
                    }
                }
            }
            // D: acc init (r,z x-parts from slot t%3) + 48 MFMAs over K=256
            const char* g0 = gb + (t%3)*32768;
            floatx4 acc[6];
#pragma unroll
            for (int g=0; g<2; ++g)
#pragma unroll
            for (int u=0; u<2; ++u) {
                const int col = g*256 + 32*w + 16*u + n16;
                const u64 gw = *(const u64*)(g0 + col*32 + quad*8);
#pragma unroll
                for (int r=0; r<4; ++r) acc[g*2+u][r] = bf2f((u16)(gw >> (16*r)));
            }
            acc[4] = (floatx4){0.f,0.f,0.f,0.f};
            acc[5] = (floatx4){0.f,0.f,0.f,0.f};
#pragma unroll
            for (int q=0; q<8; ++q) {
                short8 ah = *(const short8*)(hbP + n16*264 + q*32 + quad*8);
#pragma unroll
                for (int m=0; m<6; ++m)
                    acc[m] = __builtin_amdgcn_mfma_f32_16x16x32_bf16(ah, bh[m][q], acc[m], 0,0,0);
            }
            // E: nonlinearity, h(t) -> LDS slot (t+1)&1
            u16* hbN = hbuf + ((t+1)&1)*4224;
            const float* nxp = (const float*)(g0 + 16384);
#pragma unroll
            for (int u=0; u<2; ++u) {
                const int j = 32*w + 16*u + n16;
                const floatx4 nx4 = *(const floatx4*)(nxp + j*16 + quad*4);
#pragma unroll
                for (int r=0; r<4; ++r) {
                    const int b = quad*4 + r;
                    float rr = sigmoidf_(acc[u][r]);
                    float zz = sigmoidf_(acc[2+u][r]);
                    float nn = tanhf_(nx4[r] + rr*acc[4+u][r]);
                    float hp = bf2f(hbP[b*264 + j]);
                    float hn = (1.0f-zz)*nn + zz*hp;
                    hbN[b*264 + j] = f2bf(hn);
                }
            }
            // F: issue DMA gates(t+2) -> slot (t+2)%3, then partial drain:
            // vmcnt(4) leaves ONLY the 4 fresh DMAs in flight; all older ops
            // (h/out stores, DMA(t+1)) complete before the barrier.
            if (need2) {
                if (tg2 != (u32)(t+3)) {
                    int gd=0;
                    while (ALD(gtp + ((t+2)&31)) != (u32)(t+3)){ if(++gd>3000000) break; __builtin_amdgcn_s_sleep(1); }
                }
                const char* sg = (const char*)(gring + (size_t)(s*32 + ((t+2)&31))*GSLOT_U64);
                char* dg = gb + ((t+2)%3)*32768;
#pragma unroll
                for (int r=0; r<4; ++r) dma16(sg + (r*512+tid)*16, dg + (r*512+tid)*16);
                wait_vm4();
            } else {
                wait_vm0();
            }
            lgkm_barrier();
        }
        // epilogue: h(511)/out(511) live in slot (512&1)=0
        const u16* hbL = hbuf;
        if (s<=4) {
            if (tid < 256) {
                const int b = tid & 15, k = tid >> 4;
                u64* hq = (u64*)(hhb + (size_t)s*1048576 + (size_t)(SEQ-1)*2048);
                AST(hq + b*32 + 2*k,     *(const u64*)(hbL + b*264 + 8*k));
                AST(hq + b*32 + 2*k + 1, *(const u64*)(hbL + b*264 + 8*k + 4));
            }
        } else {
            const int off = (s==6)?256:0;
#pragma unroll
            for (int k=0;k<5;++k) {
                const int idx = tid + 512*k, b = idx >> 8, j = idx & 255;
                if (b < 10)
                    out[(size_t)(SEQ-1)*5120 + (size_t)b*512 + off + j] = bf2f(hbL[b*264 + j]);
            }
        }
        wait_vm0(); lgkm_barrier();
        if (tid==0 && s<=4) { AST(htp + 510, 511u); AST(htp + 511, 512u); }
        return;
    }

    // ================= HELPERS: gates_x producers (3 WGs/stream) =================
    int sh, t0;
    if (blk < 10)      { sh = 0;               t0 = blk - 7;      }
    else if (blk < 25) { sh = 1 + (blk-10)/3;  t0 = (blk-10)%3;   }
    else               { sh = 6;               t0 = blk - 25;     }

    const int layer = (sh==6)?5:sh, dir=(sh==6)?1:0;
    const float* wihp; int stride;
    if (layer==0){ wihp = wihl0 + (size_t)dir*768*128; stride=128; }
    else         { wihp = wihrest + ((size_t)((layer-1)*2+dir))*768*512; stride=512; }

    // 8 waves x 6 tiles: gate col = (w*6+i)*16 + n16
    short8 bxf[6][4];
#pragma unroll
    for (int i=0; i<6; ++i) {
        const int col = (w*6+i)*16 + n16;
#pragma unroll
        for (int q=0; q<4; ++q)
            bxf[i][q] = ld8f(wihp + (size_t)col*stride + q*32 + quad*8);
    }
    char* tb = (char*)smem_;               // 32 KB slot image
    const int bmA = (n16>9)?9:n16;
    const int lsrc = (sh==6)? 4 : (sh-1);

    for (int t = t0; t < SEQ; t += 3) {
        if (t >= 32) {   // ring-32 flow control vs consumer scan (lead <= 24)
            int gd=0;
            while ((int)ALD(cparr + sh) < t-24){ if(++gd>1000000) break; __builtin_amdgcn_s_sleep(8); }
        }
        short8 ax[4];
        if (sh == 0) {
            const float* xr = x + (size_t)t*1280 + (size_t)bmA*128;
#pragma unroll
            for (int q=0; q<4; ++q) ax[q] = ld8f(xr + q*32 + quad*8);
        } else {
            const int srct = (sh==6)? (SEQ-1-t) : t;
            int gd=0;
            while (ALD(tags + 256 + lsrc*512 + srct) != (u32)(srct+1)){ if(++gd>3000000) break; __builtin_amdgcn_s_sleep(4); }
            const u64* hq = (const u64*)(hhb + (size_t)lsrc*1048576 + (size_t)srct*2048);
#pragma unroll
            for (int q=0; q<4; ++q) {
                u64 a = ALD(hq + n16*32 + q*8 + quad*2);
                u64 b = ALD(hq + n16*32 + q*8 + quad*2 + 1);
                ax[q] = pk2(a, b);
            }
        }
        floatx4 acc[6];
#pragma unroll
        for (int i=0; i<6; ++i) acc[i] = (floatx4){0.f,0.f,0.f,0.f};
#pragma unroll
        for (int q=0; q<4; ++q)
#pragma unroll
            for (int i=0; i<6; ++i)
                acc[i] = __builtin_amdgcn_mfma_f32_16x16x32_bf16(ax[q], bxf[i][q], acc[i], 0,0,0);

        // slot image in LDS: rz bf16 [col<512][16], nx f32 [col-512][16]
#pragma unroll
        for (int i=0; i<6; ++i) {
            const int col = (w*6+i)*16 + n16;
            if (col < 512) *(u64*)(tb + col*32 + quad*8) = pack4bf(acc[i]);
            else           *(floatx4*)(tb + 16384 + (col-512)*64 + quad*16) = acc[i];
        }
        __syncthreads();
        u64* gq = gring + (size_t)(sh*32 + (t&31))*GSLOT_U64;
#pragma unroll
        for (int k=0;k<8;++k) AST(gq + tid*8 + k, ((const u64*)tb)[tid*8 + k]);
        wait_vm0();
        __syncthreads();
        if (tid==0) AST(tags + sh*32 + (t&31), (u32)(t+1));
        __syncthreads();
    }
}

extern "C" void kernel_launch(void* const* d_in, const int* in_sizes, int n_in,
                              void* d_out, int out_size, void* d_ws, size_t ws_size,
                              hipStream_t stream) {
    (void)in_sizes; (void)n_in; (void)out_size; (void)ws_size;
    const float* x       = (const float*)d_in[0];
    const float* wihl0   = (const float*)d_in[1];
    const float* wihrest = (const float*)d_in[2];
    const float* whh     = (const float*)d_in[3];
    float* out = (float*)d_out;
    u64* gring = (u64*)d_ws;
    u16* hhb   = (u16*)((char*)d_ws + (size_t)GRING_U64*8);
    u32* tags  = (u32*)((char*)d_ws + TAGS_OFF_B);

    // No memset: 0xAAAAAAAA poison never equals a valid tag (1..512);
    // flow-control reads cast to int (poison negative => "not yet").
    gru_pipeline<<<dim3(28), dim3(512), 0, stream>>>(x, wihl0, wihrest, whh, out,
                                                     gring, hhb, tags);
}